// Round 11
// baseline (270.733 us; speedup 1.0000x reference)
//
#include <hip/hip_runtime.h>
#include <hip/hip_fp16.h>

#define B_ 4
#define S_ 2048
#define H_ 1024
#define M_ (B_ * S_)  // 8192 flattened rows of x / q / k / v

typedef _Float16 f16;
typedef _Float16 f16x8 __attribute__((ext_vector_type(8)));
typedef _Float16 f16x4 __attribute__((ext_vector_type(4)));
typedef float f32x4 __attribute__((ext_vector_type(4)));

typedef __attribute__((address_space(3))) unsigned int* lds_u32p;
typedef const __attribute__((address_space(1))) unsigned int* gbl_u32p;

// async global->LDS, 16B per lane; LDS dest is wave-uniform base + lane*16
__device__ __forceinline__ void stage16(const f16* g, f16* l) {
  __builtin_amdgcn_global_load_lds((gbl_u32p)g, (lds_u32p)l, 16, 0, 0);
}

// convert 8 f32 (two f32x4) -> 8 f16 (RNE, identical to downconvert's cast)
// and write 16B to LDS.
#define CVW(a, b, dst)                                                       \
  {                                                                          \
    f16x8 h_;                                                                \
    h_[0] = (f16)(a)[0]; h_[1] = (f16)(a)[1];                                \
    h_[2] = (f16)(a)[2]; h_[3] = (f16)(a)[3];                                \
    h_[4] = (f16)(b)[0]; h_[5] = (f16)(b)[1];                                \
    h_[6] = (f16)(b)[2]; h_[7] = (f16)(b)[3];                                \
    *(f16x8*)(dst) = h_;                                                     \
  }

// ---------------------------------------------------------------------------
// Fused QKV projection — r0/r8 compute structure (best measured, no swizzle,
// x-major grid: r10's transpose regressed, FETCH +75% for +2us -> reverted),
// with the fp32->fp16 DOWNCONVERT FOLDED INTO STAGING (r11): A (x) and B (W)
// are loaded as f32x4 pairs to registers, converted RNE in-VALU (idle 18%
// VALUBusy absorbs it) and ds_write_b128'd to the SAME LDS layout the old
// stage16 produced. Eliminates the downconvert kernel, its launch boundary,
// and the 48MB xh/Wh intermediate round-trip. xh/Wh buffers no longer exist.
// sel==2 (V) is written TRANSPOSED to vT[b][h][t].
__global__ __launch_bounds__(256, 2)
void qkv_gemm(const float* __restrict__ x, const float* __restrict__ Wq,
              const float* __restrict__ Wk, const float* __restrict__ Wv,
              const float* __restrict__ bq, const float* __restrict__ bk,
              const float* __restrict__ bv, f16* __restrict__ qkv,
              f16* __restrict__ vT) {
  __shared__ __align__(16) f16 As[2 * 128 * 32];  // [chunk0 | chunk1]
  __shared__ __align__(16) f16 Bs[2 * 128 * 32];
  const int t = threadIdx.x;
  const int wave = t >> 6, lane = t & 63;
  const int quad = lane >> 4, l16 = lane & 15;
  const int wm = (wave & 1) * 64, wn = (wave >> 1) * 64;
  const int sel = blockIdx.y >> 3;             // 0=q 1=k 2=v
  const int ntile = (blockIdx.y & 7) * 128;
  const int mtile = blockIdx.x * 128;

  const float* Wsel = sel == 0 ? Wq : (sel == 1 ? Wk : Wv);
  const float* Ab = x + (long)mtile * H_;
  const float* Bb = Wsel + (long)ntile * H_;

  const int r0 = t >> 2;        // staging row 0..63
  const int c8 = (t & 3) * 8;   // staging col (elements)

  f32x4 acc[4][4] = {};

  for (int k0 = 0; k0 < H_; k0 += 64) {
    __syncthreads();
    // ---- staging: 16 f32x4 loads issued back-to-back, then cvt+ds_write ---
    const float* pa0 = Ab + (long)r0 * H_ + k0 + c8;
    const float* pa1 = Ab + (long)(r0 + 64) * H_ + k0 + c8;
    const float* pb0 = Bb + (long)r0 * H_ + k0 + c8;
    const float* pb1 = Bb + (long)(r0 + 64) * H_ + k0 + c8;
    f32x4 r[16];
    r[ 0] = ((const f32x4*)pa0)[0];        r[ 1] = ((const f32x4*)pa0)[1];
    r[ 2] = ((const f32x4*)pa1)[0];        r[ 3] = ((const f32x4*)pa1)[1];
    r[ 4] = ((const f32x4*)(pa0 + 32))[0]; r[ 5] = ((const f32x4*)(pa0 + 32))[1];
    r[ 6] = ((const f32x4*)(pa1 + 32))[0]; r[ 7] = ((const f32x4*)(pa1 + 32))[1];
    r[ 8] = ((const f32x4*)pb0)[0];        r[ 9] = ((const f32x4*)pb0)[1];
    r[10] = ((const f32x4*)pb1)[0];        r[11] = ((const f32x4*)pb1)[1];
    r[12] = ((const f32x4*)(pb0 + 32))[0]; r[13] = ((const f32x4*)(pb0 + 32))[1];
    r[14] = ((const f32x4*)(pb1 + 32))[0]; r[15] = ((const f32x4*)(pb1 + 32))[1];
    CVW(r[ 0], r[ 1], As + t * 8);          // rows 0..63,  k chunk0
    CVW(r[ 2], r[ 3], As + 2048 + t * 8);   // rows 64..127,k chunk0
    CVW(r[ 4], r[ 5], As + 4096 + t * 8);   // rows 0..63,  k chunk1
    CVW(r[ 6], r[ 7], As + 6144 + t * 8);   // rows 64..127,k chunk1
    CVW(r[ 8], r[ 9], Bs + t * 8);
    CVW(r[10], r[11], Bs + 2048 + t * 8);
    CVW(r[12], r[13], Bs + 4096 + t * 8);
    CVW(r[14], r[15], Bs + 6144 + t * 8);
    __syncthreads();
#pragma unroll
    for (int kk = 0; kk < 2; kk++) {
      f16x8 ah[4], bh[4];
#pragma unroll
      for (int i = 0; i < 4; i++) {
        ah[i] = *(const f16x8*)&As[kk * 4096 + (wm + i * 16 + l16) * 32 + quad * 8];
        bh[i] = *(const f16x8*)&Bs[kk * 4096 + (wn + i * 16 + l16) * 32 + quad * 8];
      }
#pragma unroll
      for (int i = 0; i < 4; i++)
#pragma unroll
        for (int j = 0; j < 4; j++)
          acc[i][j] = __builtin_amdgcn_mfma_f32_16x16x32_f16(ah[i], bh[j], acc[i][j], 0, 0, 0);
    }
  }

  const float* bias = sel == 0 ? bq : (sel == 1 ? bk : bv);
  if (sel == 2) {
    // V transposed: vT[(b*H + n)*S + t_pos], b = m>>11, t_pos = m&2047.
#pragma unroll
    for (int j = 0; j < 4; j++) {
      int n = ntile + wn + j * 16 + l16;
      float bb = bias[n];
#pragma unroll
      for (int i = 0; i < 4; i++) {
        int m = mtile + wm + i * 16 + quad * 4;
        f16x4 pack;
#pragma unroll
        for (int r = 0; r < 4; r++) pack[r] = (f16)(acc[i][j][r] + bb);
        *(f16x4*)&vT[((long)(m >> 11) * H_ + n) * S_ + (m & 2047)] = pack;
      }
    }
  } else {
    f16* out = qkv + (long)sel * M_ * H_;
#pragma unroll
    for (int j = 0; j < 4; j++) {
      int n = ntile + wn + j * 16 + l16;
      float bb = bias[n];
#pragma unroll
      for (int i = 0; i < 4; i++) {
        int m = mtile + wm + i * 16 + quad * 4;
#pragma unroll
        for (int r = 0; r < 4; r++)
          out[(long)(m + r) * H_ + n] = (f16)(acc[i][j][r] + bb);
      }
    }
  }
}

// ---------------------------------------------------------------------------
// Generic batched NT fp16 GEMM — round-0 structure + chunk-XOR swizzle
// (r8 vs r7 A/B: ~-5us across scores+PV).
// Swizzle: 16B chunk c of row r holds global chunk c ^ ((r>>1)&3); applied
// on the global SOURCE of stage16 (LDS dest linear) and on ds_read address.
// C[z][m][n] = alpha * sum_k A[z][m][k]*B[z][n][k]
template <int OUT_F16>
__global__ __launch_bounds__(256, 2)
void gemm_nt(const f16* __restrict__ A, const f16* __restrict__ Bm,
             void* __restrict__ C, int lda, int ldb, int ldc, int K,
             long sA, long sB, long sC, float alpha) {
  __shared__ __align__(16) f16 As[2 * 128 * 32];
  __shared__ __align__(16) f16 Bs[2 * 128 * 32];
  const int t = threadIdx.x;
  const int wave = t >> 6, lane = t & 63;
  const int quad = lane >> 4, l16 = lane & 15;
  const int wm = (wave & 1) * 64, wn = (wave >> 1) * 64;
  const f16* Ab = A + blockIdx.z * sA + (long)blockIdx.x * 128 * lda;
  const f16* Bb = Bm + blockIdx.z * sB + (long)blockIdx.y * 128 * ldb;
  const int r0 = t >> 2;
  const int c8 = ((t & 3) ^ ((r0 >> 1) & 3)) * 8;    // pre-swizzled source
  const int swz8 = (quad ^ ((l16 >> 1) & 3)) * 8;    // swizzled ds_read
  f32x4 acc[4][4] = {};
  for (int k0 = 0; k0 < K; k0 += 64) {
    __syncthreads();
    stage16(Ab + (long)r0 * lda + k0 + c8,             As + t * 8);
    stage16(Ab + (long)(r0 + 64) * lda + k0 + c8,      As + 2048 + t * 8);
    stage16(Ab + (long)r0 * lda + k0 + 32 + c8,        As + 4096 + t * 8);
    stage16(Ab + (long)(r0 + 64) * lda + k0 + 32 + c8, As + 6144 + t * 8);
    stage16(Bb + (long)r0 * ldb + k0 + c8,             Bs + t * 8);
    stage16(Bb + (long)(r0 + 64) * ldb + k0 + c8,      Bs + 2048 + t * 8);
    stage16(Bb + (long)r0 * ldb + k0 + 32 + c8,        Bs + 4096 + t * 8);
    stage16(Bb + (long)(r0 + 64) * ldb + k0 + 32 + c8, Bs + 6144 + t * 8);
    __syncthreads();
#pragma unroll
    for (int kk = 0; kk < 2; kk++) {
      f16x8 af[4], bf[4];
#pragma unroll
      for (int i = 0; i < 4; i++) {
        af[i] = *(const f16x8*)&As[kk * 4096 + (wm + i * 16 + l16) * 32 + swz8];
        bf[i] = *(const f16x8*)&Bs[kk * 4096 + (wn + i * 16 + l16) * 32 + swz8];
      }
#pragma unroll
      for (int i = 0; i < 4; i++)
#pragma unroll
        for (int j = 0; j < 4; j++)
          acc[i][j] = __builtin_amdgcn_mfma_f32_16x16x32_f16(af[i], bf[j], acc[i][j], 0, 0, 0);
    }
  }
  const long mb = (long)blockIdx.x * 128 + wm;
  const long nb = (long)blockIdx.y * 128 + wn;
#pragma unroll
  for (int i = 0; i < 4; i++)
#pragma unroll
    for (int j = 0; j < 4; j++) {
      long m = mb + i * 16 + quad * 4;
      long n = nb + j * 16 + l16;
#pragma unroll
      for (int r = 0; r < 4; r++) {
        float v = acc[i][j][r] * alpha;
        if (OUT_F16)
          ((f16*)C)[blockIdx.z * sC + (m + r) * ldc + n] = (f16)v;
        else
          ((float*)C)[blockIdx.z * sC + (m + r) * ldc + n] = v;
      }
    }
}

// ---------------------------------------------------------------------------
// Wave-per-row softmax + fp16 quantize: 4 rows per 256-thread block.
// No LDS, no __syncthreads, pure shfl reductions; 64B/lane vectorized I/O.
// (r9 lesson: do NOT fuse the exp into PV — transform must run once per
// element; in PV it is 16x redundant and VALU-bound, 171us vs ~48us split.)
__global__ __launch_bounds__(256) void softmax_w(f16* __restrict__ sc) {
  const int wave = threadIdx.x >> 6, lane = threadIdx.x & 63;
  const long row = (long)blockIdx.x * 4 + wave;
  f16* p = sc + row * S_;
  f16x8 v[4];
#pragma unroll
  for (int i = 0; i < 4; ++i) v[i] = ((const f16x8*)p)[i * 64 + lane];
  float f[32];
  float m = -3.0e38f;
#pragma unroll
  for (int i = 0; i < 4; ++i)
#pragma unroll
    for (int c = 0; c < 8; ++c) {
      float x = (float)v[i][c];
      f[i * 8 + c] = x;
      m = fmaxf(m, x);
    }
#pragma unroll
  for (int o = 32; o > 0; o >>= 1) m = fmaxf(m, __shfl_xor(m, o));
  float s = 0.f;
#pragma unroll
  for (int i = 0; i < 32; ++i) { f[i] = __expf(f[i] - m); s += f[i]; }
#pragma unroll
  for (int o = 32; o > 0; o >>= 1) s += __shfl_xor(s, o);
  const float inv = 1.0f / s;
#pragma unroll
  for (int i = 0; i < 4; ++i) {
    f16x8 ov;
#pragma unroll
    for (int c = 0; c < 8; ++c) ov[c] = (f16)(f[i * 8 + c] * inv);
    ((f16x8*)p)[i * 64 + lane] = ov;
  }
}

// ---------------------------------------------------------------------------
extern "C" void kernel_launch(void* const* d_in, const int* in_sizes, int n_in,
                              void* d_out, int out_size, void* d_ws, size_t ws_size,
                              hipStream_t stream) {
  (void)in_sizes; (void)n_in; (void)out_size; (void)ws_size;
  const float* x  = (const float*)d_in[0];
  const float* Wq = (const float*)d_in[1];
  const float* bq = (const float*)d_in[2];
  const float* Wk = (const float*)d_in[3];
  const float* bk = (const float*)d_in[4];
  const float* Wv = (const float*)d_in[5];
  const float* bv = (const float*)d_in[6];

  char* ws = (char*)d_ws;
  f16* qkv = (f16*)ws; ws += (size_t)2 * M_ * H_ * 2;      // 32 MiB (q, k)
  f16* vT  = (f16*)ws; ws += (size_t)B_ * H_ * S_ * 2;     // 16 MiB
  f16* sc  = (f16*)ws; ws += (size_t)B_ * S_ * S_ * 2;     // 32 MiB (scores, then attn in-place)

  // 1) fused QKV projection + bias + quantize, with fp32->fp16 conversion
  //    folded into staging (downconvert kernel + xh/Wh round-trip removed);
  //    V written transposed.
  qkv_gemm<<<dim3(64, 24), 256, 0, stream>>>(
      x, Wq, Wk, Wv, bq, bk, bv, qkv, vT);

  // 2) scores = quantize(q @ k^T / 32), per batch — swizzled gemm_nt
  gemm_nt<1><<<dim3(16, 16, 4), 256, 0, stream>>>(
      qkv, qkv + (size_t)M_ * H_, sc, H_, H_, S_, H_,
      (long)S_ * H_, (long)S_ * H_, (long)S_ * S_, 0.03125f);

  // 3) attn = quantize(softmax(scores)) in-place — wave-per-row
  softmax_w<<<M_ / 4, 256, 0, stream>>>(sc);

  // 4) out = attn @ vT^T (fp32 straight to d_out) — swizzled gemm_nt
  gemm_nt<0><<<dim3(16, 8, 4), 256, 0, stream>>>(
      sc, vT, d_out, S_, S_, H_, S_,
      (long)S_ * S_, (long)H_ * S_, (long)S_ * H_, 1.0f);
}